// Round 4
// baseline (670.843 us; speedup 1.0000x reference)
//
#include <hip/hip_runtime.h>
#include <hip/hip_bf16.h>
#include <math.h>

#define NPTS   8192
#define KNN    16
#define G      16
#define NCELL  (G * G * G)
#define LISTCAP 2048

// Fixed standard-normal quantile boundaries (i/16). Only affect load balance,
// never correctness (bounds are computed from these actual values).
__constant__ float c_B[17] = {
    -1e30f,
    -1.5341205f, -1.1503494f, -0.8871466f, -0.6744898f, -0.4887764f,
    -0.3186394f, -0.1573107f,  0.0f,        0.1573107f,  0.3186394f,
     0.4887764f,  0.6744898f,  0.8871466f,  1.1503494f,  1.5341205f,
     1e30f
};

__device__ __forceinline__ int cellOf(float v) {
    int c = 0;
#pragma unroll
    for (int i = 1; i <= 15; ++i) c += (v >= c_B[i]) ? 1 : 0;
    return c;
}

// prev-lane within each 16-lane row (DPP row_shr:1); row-head lanes masked by caller.
__device__ __forceinline__ float dpp_prev_f(float v) {
    int r = __builtin_amdgcn_update_dpp(0, __float_as_int(v), 0x111, 0xF, 0xF, false);
    return __int_as_float(r);
}
__device__ __forceinline__ int dpp_prev_i(int v) {
    return __builtin_amdgcn_update_dpp(0, v, 0x111, 0xF, 0xF, false);
}

// ---------------- Kernel A: bin points into cells, cell-sort (one block per cloud) ----
__global__ __launch_bounds__(1024) void bin_kernel(
    const float* __restrict__ x, const float* __restrict__ y,
    float4* __restrict__ Ps, unsigned int* __restrict__ starts,
    unsigned short* __restrict__ cellids, unsigned short* __restrict__ origids) {

    __shared__ unsigned int   cnts[NCELL];
    __shared__ unsigned int   offs[NCELL];
    __shared__ unsigned int   scanbuf[1024];
    __shared__ unsigned short cellbuf[NPTS];

    const int tid   = threadIdx.x;
    const int cloud = blockIdx.x;
    const float* __restrict__ src = (cloud < 2 ? x : y) + (size_t)(cloud & 1) * NPTS * 3;

    for (int i = tid; i < NCELL; i += 1024) cnts[i] = 0;
    __syncthreads();

    for (int p = tid; p < NPTS; p += 1024) {
        float px = src[3 * p], py = src[3 * p + 1], pz = src[3 * p + 2];
        int c = (cellOf(px) * G + cellOf(py)) * G + cellOf(pz);
        cellbuf[p] = (unsigned short)c;
        atomicAdd(&cnts[c], 1u);
    }
    __syncthreads();

    // block scan: thread t owns cells 4t..4t+3
    unsigned int c0 = cnts[4 * tid], c1 = cnts[4 * tid + 1];
    unsigned int c2 = cnts[4 * tid + 2], c3 = cnts[4 * tid + 3];
    unsigned int ssum = c0 + c1 + c2 + c3;
    scanbuf[tid] = ssum;
    __syncthreads();
    for (int d = 1; d < 1024; d <<= 1) {
        unsigned int v = scanbuf[tid];
        unsigned int w = (tid >= d) ? scanbuf[tid - d] : 0;
        __syncthreads();
        scanbuf[tid] = v + w;
        __syncthreads();
    }
    unsigned int excl = scanbuf[tid] - ssum;
    unsigned int e0 = excl, e1 = e0 + c0, e2 = e1 + c1, e3 = e2 + c2;
    offs[4 * tid] = e0; offs[4 * tid + 1] = e1;
    offs[4 * tid + 2] = e2; offs[4 * tid + 3] = e3;
    unsigned int* sg = starts + cloud * 4100;
    sg[4 * tid] = e0; sg[4 * tid + 1] = e1; sg[4 * tid + 2] = e2; sg[4 * tid + 3] = e3;
    if (tid == 0) sg[NCELL] = NPTS;
    __syncthreads();

    for (int p = tid; p < NPTS; p += 1024) {
        int c = cellbuf[p];
        unsigned int pos = atomicAdd(&offs[c], 1u);
        float px = src[3 * p], py = src[3 * p + 1], pz = src[3 * p + 2];
        Ps[(cloud << 13) + pos] = make_float4(-2.f * px, -2.f * py, -2.f * pz,
                                              px * px + py * py + pz * pz);
        cellids[(cloud << 13) + pos] = (unsigned short)c;
        origids[(cloud << 13) + pos] = (unsigned short)p;
    }
}

// ---------------- Kernel B: grid kNN + covariance, one wave per query ----------------
__global__ __launch_bounds__(512) void knn_cov_kernel(
    const float4* __restrict__ Ps, const unsigned int* __restrict__ starts,
    const unsigned short* __restrict__ cellids, const unsigned short* __restrict__ origids,
    float* __restrict__ cov) {

    __shared__ unsigned int   sStarts[NCELL + 1];   // 16388 B
    __shared__ unsigned short slist[8][LISTCAP];    // 32768 B

    const int tid  = threadIdx.x;
    const int lane = tid & 63;
    const int wv   = tid >> 6;
    const int cloud = blockIdx.x >> 10;
    const int s     = ((blockIdx.x << 3) | wv) & (NPTS - 1);   // sorted position in cloud

    const unsigned int* sg = starts + cloud * 4100;
    for (int i = tid; i <= NCELL; i += 512) sStarts[i] = sg[i];
    __syncthreads();

    const float4* __restrict__ Pc = Ps + (cloud << 13);
    const float4 qp = Pc[s];
    const float sqq = qp.w;
    const float qx = -0.5f * qp.x, qy = -0.5f * qp.y, qz = -0.5f * qp.z;
    const int mycell = cellids[(cloud << 13) + s];
    const int cx = mycell >> 8, cy = (mycell >> 4) & 15, cz = mycell & 15;

    float valV = 3.4e38f;   // distributed sorted top-16 d2 (lanes 0..15 per row, replicated)
    int   idxV = 0;         // matching sorted positions
    float thr  = 3.4e38f;   // current 16th-best d2 (wave-uniform)
    bool seeded = false;
    bool ovf = false;

    // Process one 64-candidate chunk: per-lane (pos, valid).
    auto do_chunk = [&](int pos, bool valid) {
        float4 f = Pc[pos];
        float d2 = fmaf(qx, f.x, fmaf(qy, f.y, fmaf(qz, f.z, sqq + f.w)));
        if (!valid) d2 = 3.4e38f;
        if (!seeded) {
            // 64-lane bitonic sort (key d2, payload pos), ascending.
            float k = d2; int p = pos;
#pragma unroll
            for (int size = 2; size <= 64; size <<= 1) {
#pragma unroll
                for (int stride = size >> 1; stride >= 1; stride >>= 1) {
                    float ok = __shfl_xor(k, stride);
                    int   op = __shfl_xor(p, stride);
                    bool up = ((lane & size) == 0);
                    bool lower = ((lane & stride) == 0);
                    bool want_min = (up == lower);
                    bool take = want_min ? (ok < k) : (ok > k);
                    k = take ? ok : k;
                    p = take ? op : p;
                }
            }
            valV = __shfl(k, lane & 15);
            idxV = __shfl(p, lane & 15);
            thr  = __shfl(k, 15);
            seeded = true;
        } else {
            unsigned long long m = __ballot(d2 < thr);
            if (m) {
                do {
                    int l = __builtin_ctzll(m); m &= m - 1;
                    float sv = __int_as_float(
                        __builtin_amdgcn_readlane(__float_as_int(d2), l));
                    int sj = __builtin_amdgcn_readlane(pos, l);
                    float pv = dpp_prev_f(valV);
                    int   pi = dpp_prev_i(idxV);
                    bool keep  = (valV <= sv);                 // no-op-safe if sv >= valV[15]
                    bool fromv = ((lane & 15) == 0) || (pv <= sv);
                    float nv = keep ? valV : (fromv ? sv : pv);
                    int   ni = keep ? idxV : (fromv ? sj : pi);
                    valV = nv; idxV = ni;
                } while (m);
                thr = __int_as_float(__builtin_amdgcn_readlane(__float_as_int(valV), 15));
            }
        }
    };

    // Gather + scan all cells of ring r (exact) or rings <= r (!exact).
    auto gather_cells = [&](int r, bool exact) {
        const int side = 2 * r + 1;
        const int n3 = side * side * side;
        for (int base = 0; base < n3; base += 64) {
            int id = base + lane;
            unsigned int start = 0; int cnt = 0;
            if (id < n3) {
                unsigned int uid = (unsigned int)id;
                int iz = (int)(uid % (unsigned)side);
                unsigned int t2 = uid / (unsigned)side;
                int iy = (int)(t2 % (unsigned)side);
                int ix = (int)(t2 / (unsigned)side);
                int dx = ix - r, dy = iy - r, dz = iz - r;
                int mx = max(abs(dx), max(abs(dy), abs(dz)));
                int nx_ = cx + dx, ny_ = cy + dy, nz_ = cz + dz;
                bool ok = (!exact || mx == r) &&
                          ((unsigned)nx_ < G) && ((unsigned)ny_ < G) && ((unsigned)nz_ < G);
                if (ok) {
                    int cidx = (nx_ * G + ny_) * G + nz_;
                    start = sStarts[cidx];
                    cnt = (int)(sStarts[cidx + 1] - start);
                }
            }
            int incl = cnt;
#pragma unroll
            for (int d = 1; d < 64; d <<= 1) {
                int u = __shfl_up(incl, d);
                incl += (lane >= d) ? u : 0;
            }
            int T = __shfl(incl, 63);
            int excl = incl - cnt;
            if (T > LISTCAP) { ovf = true; return; }
            for (int t2 = 0; t2 < cnt; ++t2)
                slist[wv][excl + t2] = (unsigned short)(start + t2);
            __asm__ volatile("s_waitcnt lgkmcnt(0)" ::: "memory");
            for (int b = 0; b < T; b += 64) {
                int li = b + lane;
                int pos = (li < T) ? (int)slist[wv][li] : 0;
                do_chunk(pos, li < T);
            }
        }
    };

    gather_cells(1, false);   // rings 0+1 (27 cells)
    if (!ovf) {
        for (int r = 2; r <= 15; ++r) {
            float L = 1e30f;
            if (cx - r >= 0) L = fminf(L, qx - c_B[cx - r + 1]);
            if (cx + r <= 15) L = fminf(L, c_B[cx + r] - qx);
            if (cy - r >= 0) L = fminf(L, qy - c_B[cy - r + 1]);
            if (cy + r <= 15) L = fminf(L, c_B[cy + r] - qy);
            if (cz - r >= 0) L = fminf(L, qz - c_B[cz - r + 1]);
            if (cz + r <= 15) L = fminf(L, c_B[cz + r] - qz);
            if (thr <= L * L) break;      // no unvisited cell can beat the 16th best
            gather_cells(r, true);
            if (ovf) break;
        }
    }
    if (ovf) {   // pathological fallback: exact full rescan
        valV = 3.4e38f; idxV = 0; thr = 3.4e38f; seeded = false;
        for (int b = 0; b < NPTS; b += 64) do_chunk(b + lane, true);
    }

    // Covariance of the 16 selected (each lane of a 16-row holds one neighbor).
    float4 nf = Pc[idxV];
    float nx = -0.5f * nf.x, ny = -0.5f * nf.y, nz = -0.5f * nf.z;

    float mx = nx, my = ny, mz = nz;
#pragma unroll
    for (int w = 1; w < 16; w <<= 1) {
        mx += __shfl_xor(mx, w);
        my += __shfl_xor(my, w);
        mz += __shfl_xor(mz, w);
    }
    const float invk = 1.0f / KNN;
    mx *= invk; my *= invk; mz *= invk;

    float dx = nx - mx, dy = ny - my, dz = nz - mz;
    float c00 = dx * dx, c01 = dx * dy, c02 = dx * dz;
    float c11 = dy * dy, c12 = dy * dz, c22 = dz * dz;
#pragma unroll
    for (int w = 1; w < 16; w <<= 1) {
        c00 += __shfl_xor(c00, w); c01 += __shfl_xor(c01, w); c02 += __shfl_xor(c02, w);
        c11 += __shfl_xor(c11, w); c12 += __shfl_xor(c12, w); c22 += __shfl_xor(c22, w);
    }

    if (lane == 0) {
        int orig = origids[(cloud << 13) + s];
        float* cp = cov + ((size_t)(cloud << 13) + orig) * 6;
        cp[0] = c00 * invk; cp[1] = c01 * invk; cp[2] = c02 * invk;
        cp[3] = c11 * invk; cp[4] = c12 * invk; cp[5] = c22 * invk;
    }
}

// ---------------- eig + reduce (unchanged) ------------------------------------------
__global__ __launch_bounds__(256) void eig_kernel(const float* __restrict__ cov,
                                                  float* __restrict__ er) {
    int i = blockIdx.x * 256 + threadIdx.x;
    if (i >= 4 * NPTS) return;
    const float* cp = cov + (size_t)i * 6;
    double a00 = cp[0], a01 = cp[1], a02 = cp[2];
    double a11 = cp[3], a12 = cp[4], a22 = cp[5];

    double qm = (a00 + a11 + a22) * (1.0 / 3.0);
    double p1 = a01 * a01 + a02 * a02 + a12 * a12;
    double b00 = a00 - qm, b11 = a11 - qm, b22 = a22 - qm;
    double p2 = b00 * b00 + b11 * b11 + b22 * b22 + 2.0 * p1;

    double ratio;
    if (p2 <= 0.0) {
        ratio = 1.0;
    } else {
        double p = sqrt(p2 * (1.0 / 6.0));
        double inv = 1.0 / p;
        double m00 = b00 * inv, m11 = b11 * inv, m22 = b22 * inv;
        double m01 = a01 * inv, m02 = a02 * inv, m12 = a12 * inv;
        double detB = m00 * (m11 * m22 - m12 * m12)
                    - m01 * (m01 * m22 - m12 * m02)
                    + m02 * (m01 * m12 - m11 * m02);
        double r = 0.5 * detB;
        r = fmin(1.0, fmax(-1.0, r));
        double phi = acos(r) * (1.0 / 3.0);
        double e1 = qm + 2.0 * p * cos(phi);
        double e3 = qm + 2.0 * p * cos(phi + 2.0943951023931953);
        double e2 = 3.0 * qm - e1 - e3;
        ratio = e1 / e2;
    }
    er[i] = (float)ratio;
}

__global__ __launch_bounds__(256) void reduce_kernel(const float* __restrict__ er,
                                                     float* __restrict__ out) {
    __shared__ double sbuf[256];
    double acc = 0.0;
    const int total = 2 * NPTS;
    for (int i = threadIdx.x; i < total; i += 256) {
        double d = (double)er[i] - (double)er[total + i];
        acc += d * d;
    }
    sbuf[threadIdx.x] = acc;
    __syncthreads();
    for (int s2 = 128; s2 > 0; s2 >>= 1) {
        if (threadIdx.x < s2) sbuf[threadIdx.x] += sbuf[threadIdx.x + s2];
        __syncthreads();
    }
    if (threadIdx.x == 0) out[0] = (float)(sbuf[0] / (double)total);
}

extern "C" void kernel_launch(void* const* d_in, const int* in_sizes, int n_in,
                              void* d_out, int out_size, void* d_ws, size_t ws_size,
                              hipStream_t stream) {
    const float* x = (const float*)d_in[0];
    const float* y = (const float*)d_in[1];
    char* ws = (char*)d_ws;

    float4*         Ps      = (float4*)(ws);                         // 524288 B
    unsigned int*   starts  = (unsigned int*)(ws + 524288);          // 65600 B
    unsigned short* cellids = (unsigned short*)(ws + 589888);        // 65536 B
    unsigned short* origids = (unsigned short*)(ws + 655424);        // 65536 B
    float*          cov     = (float*)(ws + 720960);                 // 786432 B
    float*          er      = (float*)(ws + 1507392);                // 131072 B
    float*          out     = (float*)d_out;

    bin_kernel<<<4, 1024, 0, stream>>>(x, y, Ps, starts, cellids, origids);
    knn_cov_kernel<<<4096, 512, 0, stream>>>(Ps, starts, cellids, origids, cov);
    eig_kernel<<<(4 * NPTS + 255) / 256, 256, 0, stream>>>(cov, er);
    reduce_kernel<<<1, 256, 0, stream>>>(er, out);
}

// Round 5
// 140.808 us; speedup vs baseline: 4.7642x; 4.7642x over previous
//
#include <hip/hip_runtime.h>
#include <hip/hip_bf16.h>
#include <math.h>

#define NPTS   8192
#define KNN    16
#define G      16
#define NCELL  (G * G * G)
#define NCHUNK 128              // 64-point chunks per cloud

// Fixed standard-normal quantile boundaries (i/16). Only affect load balance,
// never correctness.
__constant__ float c_B[17] = {
    -1e30f,
    -1.5341205f, -1.1503494f, -0.8871466f, -0.6744898f, -0.4887764f,
    -0.3186394f, -0.1573107f,  0.0f,        0.1573107f,  0.3186394f,
     0.4887764f,  0.6744898f,  0.8871466f,  1.1503494f,  1.5341205f,
     1e30f
};

__device__ __forceinline__ int cellOf(float v) {
    int c = 0;
#pragma unroll
    for (int i = 1; i <= 15; ++i) c += (v >= c_B[i]) ? 1 : 0;
    return c;
}

// spread 4 bits to positions 0,3,6,9
__device__ __forceinline__ int spread3(int v) {
    v = (v | (v << 4)) & 0x0C3;
    v = (v | (v << 2)) & 0x249;
    return v;
}

// prev-lane within each 16-lane row (DPP row_shr:1); row-head lanes masked by caller.
__device__ __forceinline__ float dpp_prev_f(float v) {
    int r = __builtin_amdgcn_update_dpp(0, __float_as_int(v), 0x111, 0xF, 0xF, false);
    return __int_as_float(r);
}
__device__ __forceinline__ int dpp_prev_i(int v) {
    return __builtin_amdgcn_update_dpp(0, v, 0x111, 0xF, 0xF, false);
}

// ---------------- Kernel A: Morton-bin + sort + chunk AABBs (one block per cloud) ----
__global__ __launch_bounds__(1024) void bin_kernel(
    const float* __restrict__ x, const float* __restrict__ y,
    float4* __restrict__ Ps, unsigned short* __restrict__ origids,
    float* __restrict__ aabbG /* [4][6][NCHUNK] */) {

    __shared__ unsigned int   cnts[NCELL];
    __shared__ unsigned int   offs[NCELL];
    __shared__ unsigned int   scanbuf[1024];
    __shared__ unsigned short cellbuf[NPTS];

    const int tid   = threadIdx.x;
    const int cloud = blockIdx.x;
    const float* __restrict__ src = (cloud < 2 ? x : y) + (size_t)(cloud & 1) * NPTS * 3;

    for (int i = tid; i < NCELL; i += 1024) cnts[i] = 0;
    __syncthreads();

    for (int p = tid; p < NPTS; p += 1024) {
        float px = src[3 * p], py = src[3 * p + 1], pz = src[3 * p + 2];
        int c = (spread3(cellOf(px)) << 2) | (spread3(cellOf(py)) << 1) | spread3(cellOf(pz));
        cellbuf[p] = (unsigned short)c;
        atomicAdd(&cnts[c], 1u);
    }
    __syncthreads();

    // block scan: thread t owns cells 4t..4t+3
    unsigned int c0 = cnts[4 * tid], c1 = cnts[4 * tid + 1];
    unsigned int c2 = cnts[4 * tid + 2], c3 = cnts[4 * tid + 3];
    unsigned int ssum = c0 + c1 + c2 + c3;
    scanbuf[tid] = ssum;
    __syncthreads();
    for (int d = 1; d < 1024; d <<= 1) {
        unsigned int v = scanbuf[tid];
        unsigned int w = (tid >= d) ? scanbuf[tid - d] : 0;
        __syncthreads();
        scanbuf[tid] = v + w;
        __syncthreads();
    }
    unsigned int excl = scanbuf[tid] - ssum;
    offs[4 * tid]     = excl;
    offs[4 * tid + 1] = excl + c0;
    offs[4 * tid + 2] = excl + c0 + c1;
    offs[4 * tid + 3] = excl + c0 + c1 + c2;
    __syncthreads();

    for (int p = tid; p < NPTS; p += 1024) {
        int c = cellbuf[p];
        unsigned int pos = atomicAdd(&offs[c], 1u);
        float px = src[3 * p], py = src[3 * p + 1], pz = src[3 * p + 2];
        Ps[(cloud << 13) + pos] = make_float4(-2.f * px, -2.f * py, -2.f * pz,
                                              px * px + py * py + pz * pz);
        origids[(cloud << 13) + pos] = (unsigned short)p;
    }
    __syncthreads();

    // Chunk AABBs: wave w handles chunks w, w+16, ...
    const int wv = tid >> 6, lane = tid & 63;
    for (int c = wv; c < NCHUNK; c += 16) {
        float4 f = Ps[(cloud << 13) | (c << 6) | lane];
        float px = -0.5f * f.x, py = -0.5f * f.y, pz = -0.5f * f.z;
        float lx = px, hx = px, ly = py, hy = py, lz = pz, hz = pz;
#pragma unroll
        for (int w = 1; w < 64; w <<= 1) {
            lx = fminf(lx, __shfl_xor(lx, w)); hx = fmaxf(hx, __shfl_xor(hx, w));
            ly = fminf(ly, __shfl_xor(ly, w)); hy = fmaxf(hy, __shfl_xor(hy, w));
            lz = fminf(lz, __shfl_xor(lz, w)); hz = fmaxf(hz, __shfl_xor(hz, w));
        }
        if (lane == 0) {
            float* ab = aabbG + cloud * (6 * NCHUNK);
            ab[0 * NCHUNK + c] = lx; ab[1 * NCHUNK + c] = hx;
            ab[2 * NCHUNK + c] = ly; ab[3 * NCHUNK + c] = hy;
            ab[4 * NCHUNK + c] = lz; ab[5 * NCHUNK + c] = hz;
        }
    }
}

// ---------------- Kernel B: chunk-pruned kNN + covariance, one wave per query --------
__global__ __launch_bounds__(512) void knn_cov_kernel(
    const float4* __restrict__ Ps, const unsigned short* __restrict__ origids,
    const float* __restrict__ aabbG, float* __restrict__ cov) {

    __shared__ float sA[6 * NCHUNK];   // SoA AABB table for this block's cloud (3 KiB)

    const int tid  = threadIdx.x;
    const int lane = tid & 63;
    const int wv   = tid >> 6;
    const int cloud = blockIdx.x >> 10;
    const int s     = ((blockIdx.x << 3) | wv) & (NPTS - 1);   // sorted position

    for (int i = tid; i < 6 * NCHUNK; i += 512) sA[i] = aabbG[cloud * (6 * NCHUNK) + i];
    __syncthreads();

    const float4* __restrict__ Pc = Ps + (cloud << 13);
    const float4 qp = Pc[s];
    const float sqq = qp.w;
    const float qx = -0.5f * qp.x, qy = -0.5f * qp.y, qz = -0.5f * qp.z;
    const int co = s >> 6;   // own chunk

    float valV, thr;
    int   idxV;

    // --- Seed: 64-lane bitonic sort of own chunk (includes self) ---
    {
        int pos = (co << 6) | lane;
        float4 f = Pc[pos];
        float k = fmaf(qx, f.x, fmaf(qy, f.y, fmaf(qz, f.z, sqq + f.w)));
        int p = pos;
#pragma unroll
        for (int size = 2; size <= 64; size <<= 1) {
#pragma unroll
            for (int stride = size >> 1; stride >= 1; stride >>= 1) {
                float ok = __shfl_xor(k, stride);
                int   op = __shfl_xor(p, stride);
                bool up = ((lane & size) == 0);
                bool lower = ((lane & stride) == 0);
                bool want_min = (up == lower);
                bool take = want_min ? (ok < k) : (ok > k);
                k = take ? ok : k;
                p = take ? op : p;
            }
        }
        valV = __shfl(k, lane & 15);
        idxV = __shfl(p, lane & 15);
        thr  = __shfl(k, 15);
    }

    // --- Chunk AABB tests: 2 chunks per lane, masks per 64-chunk group ---
    unsigned long long masks[2];
    float bval[2];
#pragma unroll
    for (int g = 0; g < 2; ++g) {
        int c = (g << 6) | lane;
        float dxl = fmaxf(0.f, fmaxf(sA[c] - qx, qx - sA[NCHUNK + c]));
        float dyl = fmaxf(0.f, fmaxf(sA[2 * NCHUNK + c] - qy, qy - sA[3 * NCHUNK + c]));
        float dzl = fmaxf(0.f, fmaxf(sA[4 * NCHUNK + c] - qz, qz - sA[5 * NCHUNK + c]));
        float b = dxl * dxl + dyl * dyl + dzl * dzl;
        bval[g] = b;
        masks[g] = __ballot((b < thr) && (c != co));
    }

    // --- Scan passing chunks ---
#pragma unroll
    for (int g = 0; g < 2; ++g) {
        unsigned long long cm = masks[g];
        while (cm) {
            int l = __builtin_ctzll(cm); cm &= cm - 1;
            float bb = __int_as_float(__builtin_amdgcn_readlane(__float_as_int(bval[g]), l));
            if (bb >= thr) continue;           // thr shrank since the ballot
            int c = (g << 6) | l;
            int pos = (c << 6) | lane;
            float4 f = Pc[pos];
            float d2 = fmaf(qx, f.x, fmaf(qy, f.y, fmaf(qz, f.z, sqq + f.w)));
            unsigned long long m = __ballot(d2 < thr);
            if (m) {
                do {
                    int li = __builtin_ctzll(m); m &= m - 1;
                    float sv = __int_as_float(
                        __builtin_amdgcn_readlane(__float_as_int(d2), li));
                    int sj = __builtin_amdgcn_readlane(pos, li);
                    float pv = dpp_prev_f(valV);
                    int   pi = dpp_prev_i(idxV);
                    bool keep  = (valV <= sv);
                    bool fromv = ((lane & 15) == 0) || (pv <= sv);
                    float nv = keep ? valV : (fromv ? sv : pv);
                    int   ni = keep ? idxV : (fromv ? sj : pi);
                    valV = nv; idxV = ni;
                } while (m);
                thr = __int_as_float(__builtin_amdgcn_readlane(__float_as_int(valV), 15));
            }
        }
    }

    // --- Covariance of the 16 selected (lanes of each 16-row hold one neighbor each) ---
    float4 nf = Pc[idxV];
    float nx = -0.5f * nf.x, ny = -0.5f * nf.y, nz = -0.5f * nf.z;

    float mx = nx, my = ny, mz = nz;
#pragma unroll
    for (int w = 1; w < 16; w <<= 1) {
        mx += __shfl_xor(mx, w);
        my += __shfl_xor(my, w);
        mz += __shfl_xor(mz, w);
    }
    const float invk = 1.0f / KNN;
    mx *= invk; my *= invk; mz *= invk;

    float dx = nx - mx, dy = ny - my, dz = nz - mz;
    float c00 = dx * dx, c01 = dx * dy, c02 = dx * dz;
    float c11 = dy * dy, c12 = dy * dz, c22 = dz * dz;
#pragma unroll
    for (int w = 1; w < 16; w <<= 1) {
        c00 += __shfl_xor(c00, w); c01 += __shfl_xor(c01, w); c02 += __shfl_xor(c02, w);
        c11 += __shfl_xor(c11, w); c12 += __shfl_xor(c12, w); c22 += __shfl_xor(c22, w);
    }

    if (lane == 0) {
        int orig = origids[(cloud << 13) + s];
        float* cp = cov + ((size_t)(cloud << 13) + orig) * 6;
        cp[0] = c00 * invk; cp[1] = c01 * invk; cp[2] = c02 * invk;
        cp[3] = c11 * invk; cp[4] = c12 * invk; cp[5] = c22 * invk;
    }
}

// ---------------- eig + reduce ------------------------------------------------------
__global__ __launch_bounds__(256) void eig_kernel(const float* __restrict__ cov,
                                                  float* __restrict__ er) {
    int i = blockIdx.x * 256 + threadIdx.x;
    if (i >= 4 * NPTS) return;
    const float* cp = cov + (size_t)i * 6;
    double a00 = cp[0], a01 = cp[1], a02 = cp[2];
    double a11 = cp[3], a12 = cp[4], a22 = cp[5];

    double qm = (a00 + a11 + a22) * (1.0 / 3.0);
    double p1 = a01 * a01 + a02 * a02 + a12 * a12;
    double b00 = a00 - qm, b11 = a11 - qm, b22 = a22 - qm;
    double p2 = b00 * b00 + b11 * b11 + b22 * b22 + 2.0 * p1;

    double ratio;
    if (p2 <= 0.0) {
        ratio = 1.0;
    } else {
        double p = sqrt(p2 * (1.0 / 6.0));
        double inv = 1.0 / p;
        double m00 = b00 * inv, m11 = b11 * inv, m22 = b22 * inv;
        double m01 = a01 * inv, m02 = a02 * inv, m12 = a12 * inv;
        double detB = m00 * (m11 * m22 - m12 * m12)
                    - m01 * (m01 * m22 - m12 * m02)
                    + m02 * (m01 * m12 - m11 * m02);
        double r = 0.5 * detB;
        r = fmin(1.0, fmax(-1.0, r));
        double phi = acos(r) * (1.0 / 3.0);
        double e1 = qm + 2.0 * p * cos(phi);
        double e3 = qm + 2.0 * p * cos(phi + 2.0943951023931953);
        double e2 = 3.0 * qm - e1 - e3;
        ratio = e1 / e2;
    }
    er[i] = (float)ratio;
}

__global__ __launch_bounds__(256) void reduce_kernel(const float* __restrict__ er,
                                                     float* __restrict__ out) {
    __shared__ double sbuf[256];
    double acc = 0.0;
    const int total = 2 * NPTS;
    for (int i = threadIdx.x; i < total; i += 256) {
        double d = (double)er[i] - (double)er[total + i];
        acc += d * d;
    }
    sbuf[threadIdx.x] = acc;
    __syncthreads();
    for (int s2 = 128; s2 > 0; s2 >>= 1) {
        if (threadIdx.x < s2) sbuf[threadIdx.x] += sbuf[threadIdx.x + s2];
        __syncthreads();
    }
    if (threadIdx.x == 0) out[0] = (float)(sbuf[0] / (double)total);
}

extern "C" void kernel_launch(void* const* d_in, const int* in_sizes, int n_in,
                              void* d_out, int out_size, void* d_ws, size_t ws_size,
                              hipStream_t stream) {
    const float* x = (const float*)d_in[0];
    const float* y = (const float*)d_in[1];
    char* ws = (char*)d_ws;

    float4*         Ps      = (float4*)(ws);                    // 524288 B
    unsigned short* origids = (unsigned short*)(ws + 524288);   // 65536 B
    float*          aabbG   = (float*)(ws + 589824);            // 12288 B
    float*          cov     = (float*)(ws + 602112);            // 786432 B
    float*          er      = (float*)(ws + 1388544);           // 131072 B
    float*          out     = (float*)d_out;

    bin_kernel<<<4, 1024, 0, stream>>>(x, y, Ps, origids, aabbG);
    knn_cov_kernel<<<4096, 512, 0, stream>>>(Ps, origids, aabbG, cov);
    eig_kernel<<<(4 * NPTS + 255) / 256, 256, 0, stream>>>(cov, er);
    reduce_kernel<<<1, 256, 0, stream>>>(er, out);
}

// Round 6
// 137.754 us; speedup vs baseline: 4.8699x; 1.0222x over previous
//
#include <hip/hip_runtime.h>
#include <hip/hip_bf16.h>
#include <math.h>

#define NPTS   8192
#define KNN    16
#define G      16
#define NCELL  (G * G * G)
#define NCHUNK 128              // 64-point chunks per cloud

// Fixed standard-normal quantile boundaries (i/16). Only affect load balance,
// never correctness.
__constant__ float c_B[17] = {
    -1e30f,
    -1.5341205f, -1.1503494f, -0.8871466f, -0.6744898f, -0.4887764f,
    -0.3186394f, -0.1573107f,  0.0f,        0.1573107f,  0.3186394f,
     0.4887764f,  0.6744898f,  0.8871466f,  1.1503494f,  1.5341205f,
     1e30f
};

__device__ __forceinline__ int cellOf(float v) {
    int c = 0;
#pragma unroll
    for (int i = 1; i <= 15; ++i) c += (v >= c_B[i]) ? 1 : 0;
    return c;
}

// spread 4 bits to positions 0,3,6,9
__device__ __forceinline__ int spread3(int v) {
    v = (v | (v << 4)) & 0x0C3;
    v = (v | (v << 2)) & 0x249;
    return v;
}

// prev-lane within each 16-lane row (DPP row_shr:1); row-head lanes masked by caller.
__device__ __forceinline__ float dpp_prev_f(float v) {
    int r = __builtin_amdgcn_update_dpp(0, __float_as_int(v), 0x111, 0xF, 0xF, false);
    return __int_as_float(r);
}
__device__ __forceinline__ int dpp_prev_i(int v) {
    return __builtin_amdgcn_update_dpp(0, v, 0x111, 0xF, 0xF, false);
}

// ---------------- Kernel A: Morton-bin + sort + chunk AABBs (one block per cloud) ----
__global__ __launch_bounds__(1024) void bin_kernel(
    const float* __restrict__ x, const float* __restrict__ y,
    float4* __restrict__ Ps, unsigned short* __restrict__ origids,
    float* __restrict__ aabbG /* [4][6][NCHUNK] */) {

    __shared__ unsigned int   cnts[NCELL];
    __shared__ unsigned int   offs[NCELL];
    __shared__ unsigned int   scanbuf[1024];
    __shared__ unsigned short cellbuf[NPTS];

    const int tid   = threadIdx.x;
    const int cloud = blockIdx.x;
    const float* __restrict__ src = (cloud < 2 ? x : y) + (size_t)(cloud & 1) * NPTS * 3;

    for (int i = tid; i < NCELL; i += 1024) cnts[i] = 0;
    __syncthreads();

    for (int p = tid; p < NPTS; p += 1024) {
        float px = src[3 * p], py = src[3 * p + 1], pz = src[3 * p + 2];
        int c = (spread3(cellOf(px)) << 2) | (spread3(cellOf(py)) << 1) | spread3(cellOf(pz));
        cellbuf[p] = (unsigned short)c;
        atomicAdd(&cnts[c], 1u);
    }
    __syncthreads();

    // block scan: thread t owns cells 4t..4t+3
    unsigned int c0 = cnts[4 * tid], c1 = cnts[4 * tid + 1];
    unsigned int c2 = cnts[4 * tid + 2], c3 = cnts[4 * tid + 3];
    unsigned int ssum = c0 + c1 + c2 + c3;
    scanbuf[tid] = ssum;
    __syncthreads();
    for (int d = 1; d < 1024; d <<= 1) {
        unsigned int v = scanbuf[tid];
        unsigned int w = (tid >= d) ? scanbuf[tid - d] : 0;
        __syncthreads();
        scanbuf[tid] = v + w;
        __syncthreads();
    }
    unsigned int excl = scanbuf[tid] - ssum;
    offs[4 * tid]     = excl;
    offs[4 * tid + 1] = excl + c0;
    offs[4 * tid + 2] = excl + c0 + c1;
    offs[4 * tid + 3] = excl + c0 + c1 + c2;
    __syncthreads();

    for (int p = tid; p < NPTS; p += 1024) {
        int c = cellbuf[p];
        unsigned int pos = atomicAdd(&offs[c], 1u);
        float px = src[3 * p], py = src[3 * p + 1], pz = src[3 * p + 2];
        Ps[(cloud << 13) + pos] = make_float4(-2.f * px, -2.f * py, -2.f * pz,
                                              px * px + py * py + pz * pz);
        origids[(cloud << 13) + pos] = (unsigned short)p;
    }
    __syncthreads();

    // Chunk AABBs: wave w handles chunks w, w+16, ...
    const int wv = tid >> 6, lane = tid & 63;
    for (int c = wv; c < NCHUNK; c += 16) {
        float4 f = Ps[(cloud << 13) | (c << 6) | lane];
        float px = -0.5f * f.x, py = -0.5f * f.y, pz = -0.5f * f.z;
        float lx = px, hx = px, ly = py, hy = py, lz = pz, hz = pz;
#pragma unroll
        for (int w = 1; w < 64; w <<= 1) {
            lx = fminf(lx, __shfl_xor(lx, w)); hx = fmaxf(hx, __shfl_xor(hx, w));
            ly = fminf(ly, __shfl_xor(ly, w)); hy = fmaxf(hy, __shfl_xor(hy, w));
            lz = fminf(lz, __shfl_xor(lz, w)); hz = fmaxf(hz, __shfl_xor(hz, w));
        }
        if (lane == 0) {
            float* ab = aabbG + cloud * (6 * NCHUNK);
            ab[0 * NCHUNK + c] = lx; ab[1 * NCHUNK + c] = hx;
            ab[2 * NCHUNK + c] = ly; ab[3 * NCHUNK + c] = hy;
            ab[4 * NCHUNK + c] = lz; ab[5 * NCHUNK + c] = hz;
        }
    }
}

// ---------------- Kernel B: best-first chunk-pruned kNN + covariance, 1 wave/query ---
__global__ __launch_bounds__(256) void knn_cov_kernel(
    const float4* __restrict__ Ps, const unsigned short* __restrict__ origids,
    const float* __restrict__ aabbG, float* __restrict__ cov) {

    __shared__ float sA[6 * NCHUNK];   // SoA AABB table for this block's cloud (3 KiB)

    const int tid  = threadIdx.x;
    const int lane = tid & 63;
    const int wv   = tid >> 6;
    const int cloud = blockIdx.x >> 11;
    const int s     = ((blockIdx.x << 2) | wv) & (NPTS - 1);   // sorted position

    for (int i = tid; i < 6 * NCHUNK; i += 256) sA[i] = aabbG[cloud * (6 * NCHUNK) + i];
    __syncthreads();

    const float4* __restrict__ Pc = Ps + (cloud << 13);
    const float4 qp = Pc[s];
    const float sqq = qp.w;
    const float qx = -0.5f * qp.x, qy = -0.5f * qp.y, qz = -0.5f * qp.z;
    const int co = s >> 6;   // own chunk

    float valV, thr;
    int   idxV;

    // --- Seed: 64-lane bitonic sort of own chunk (includes self) ---
    {
        int pos = (co << 6) | lane;
        float4 f = Pc[pos];
        float k = fmaf(qx, f.x, fmaf(qy, f.y, fmaf(qz, f.z, sqq + f.w)));
        int p = pos;
#pragma unroll
        for (int size = 2; size <= 64; size <<= 1) {
#pragma unroll
            for (int stride = size >> 1; stride >= 1; stride >>= 1) {
                float ok = __shfl_xor(k, stride);
                int   op = __shfl_xor(p, stride);
                bool up = ((lane & size) == 0);
                bool lower = ((lane & stride) == 0);
                bool want_min = (up == lower);
                bool take = want_min ? (ok < k) : (ok > k);
                k = take ? ok : k;
                p = take ? op : p;
            }
        }
        valV = __shfl(k, lane & 15);
        idxV = __shfl(p, lane & 15);
        thr  = __shfl(k, 15);
    }

    // --- Chunk AABB bounds: 2 chunks per lane (groups of 64 chunk ids) ---
    float bval[2];
#pragma unroll
    for (int g = 0; g < 2; ++g) {
        int c = (g << 6) | lane;
        float dxl = fmaxf(0.f, fmaxf(sA[c] - qx, qx - sA[NCHUNK + c]));
        float dyl = fmaxf(0.f, fmaxf(sA[2 * NCHUNK + c] - qy, qy - sA[3 * NCHUNK + c]));
        float dzl = fmaxf(0.f, fmaxf(sA[4 * NCHUNK + c] - qz, qz - sA[5 * NCHUNK + c]));
        bval[g] = dxl * dxl + dyl * dyl + dzl * dzl;
    }
    unsigned long long rem0 = ~0ull, rem1 = ~0ull;
    if (co < 64) rem0 &= ~(1ull << co); else rem1 &= ~(1ull << (co - 64));

    // --- Best-first scan: always process the unvisited chunk with smallest bound ---
    for (;;) {
        unsigned long long live0 = rem0 & __ballot(bval[0] < thr);
        unsigned long long live1 = rem1 & __ballot(bval[1] < thr);
        if (!(live0 | live1)) break;

        // global argmin over live candidates: key = float_bits(bound)<<8 | chunk_id
        unsigned long long k0 = ((live0 >> lane) & 1)
            ? (((unsigned long long)__float_as_uint(bval[0]) << 8) | (unsigned)lane) : ~0ull;
        unsigned long long k1 = ((live1 >> lane) & 1)
            ? (((unsigned long long)__float_as_uint(bval[1]) << 8) | (unsigned)(64 + lane)) : ~0ull;
        unsigned long long kk = k0 < k1 ? k0 : k1;
#pragma unroll
        for (int w = 1; w < 64; w <<= 1) {
            unsigned long long ok = __shfl_xor(kk, w);
            kk = ok < kk ? ok : kk;
        }
        int cid = (int)(kk & 0xff);
        if (cid < 64) rem0 &= ~(1ull << cid); else rem1 &= ~(1ull << (cid - 64));

        // scan chunk cid
        int pos = (cid << 6) | lane;
        float4 f = Pc[pos];
        float d2 = fmaf(qx, f.x, fmaf(qy, f.y, fmaf(qz, f.z, sqq + f.w)));
        unsigned long long m = __ballot(d2 < thr);
        if (m) {
            do {
                int li = __builtin_ctzll(m); m &= m - 1;
                float sv = __int_as_float(
                    __builtin_amdgcn_readlane(__float_as_int(d2), li));
                int sj = __builtin_amdgcn_readlane(pos, li);
                float pv = dpp_prev_f(valV);
                int   pi = dpp_prev_i(idxV);
                bool keep  = (valV <= sv);
                bool fromv = ((lane & 15) == 0) || (pv <= sv);
                float nv = keep ? valV : (fromv ? sv : pv);
                int   ni = keep ? idxV : (fromv ? sj : pi);
                valV = nv; idxV = ni;
            } while (m);
            thr = __int_as_float(__builtin_amdgcn_readlane(__float_as_int(valV), 15));
        }
    }

    // --- Covariance of the 16 selected (lanes of each 16-row hold one neighbor each) ---
    float4 nf = Pc[idxV];
    float nx = -0.5f * nf.x, ny = -0.5f * nf.y, nz = -0.5f * nf.z;

    float mx = nx, my = ny, mz = nz;
#pragma unroll
    for (int w = 1; w < 16; w <<= 1) {
        mx += __shfl_xor(mx, w);
        my += __shfl_xor(my, w);
        mz += __shfl_xor(mz, w);
    }
    const float invk = 1.0f / KNN;
    mx *= invk; my *= invk; mz *= invk;

    float dx = nx - mx, dy = ny - my, dz = nz - mz;
    float c00 = dx * dx, c01 = dx * dy, c02 = dx * dz;
    float c11 = dy * dy, c12 = dy * dz, c22 = dz * dz;
#pragma unroll
    for (int w = 1; w < 16; w <<= 1) {
        c00 += __shfl_xor(c00, w); c01 += __shfl_xor(c01, w); c02 += __shfl_xor(c02, w);
        c11 += __shfl_xor(c11, w); c12 += __shfl_xor(c12, w); c22 += __shfl_xor(c22, w);
    }

    if (lane == 0) {
        int orig = origids[(cloud << 13) + s];
        float* cp = cov + ((size_t)(cloud << 13) + orig) * 6;
        cp[0] = c00 * invk; cp[1] = c01 * invk; cp[2] = c02 * invk;
        cp[3] = c11 * invk; cp[4] = c12 * invk; cp[5] = c22 * invk;
    }
}

// ---------------- eig + reduce ------------------------------------------------------
__global__ __launch_bounds__(256) void eig_kernel(const float* __restrict__ cov,
                                                  float* __restrict__ er) {
    int i = blockIdx.x * 256 + threadIdx.x;
    if (i >= 4 * NPTS) return;
    const float* cp = cov + (size_t)i * 6;
    double a00 = cp[0], a01 = cp[1], a02 = cp[2];
    double a11 = cp[3], a12 = cp[4], a22 = cp[5];

    double qm = (a00 + a11 + a22) * (1.0 / 3.0);
    double p1 = a01 * a01 + a02 * a02 + a12 * a12;
    double b00 = a00 - qm, b11 = a11 - qm, b22 = a22 - qm;
    double p2 = b00 * b00 + b11 * b11 + b22 * b22 + 2.0 * p1;

    double ratio;
    if (p2 <= 0.0) {
        ratio = 1.0;
    } else {
        double p = sqrt(p2 * (1.0 / 6.0));
        double inv = 1.0 / p;
        double m00 = b00 * inv, m11 = b11 * inv, m22 = b22 * inv;
        double m01 = a01 * inv, m02 = a02 * inv, m12 = a12 * inv;
        double detB = m00 * (m11 * m22 - m12 * m12)
                    - m01 * (m01 * m22 - m12 * m02)
                    + m02 * (m01 * m12 - m11 * m02);
        double r = 0.5 * detB;
        r = fmin(1.0, fmax(-1.0, r));
        double phi = acos(r) * (1.0 / 3.0);
        double e1 = qm + 2.0 * p * cos(phi);
        double e3 = qm + 2.0 * p * cos(phi + 2.0943951023931953);
        double e2 = 3.0 * qm - e1 - e3;
        ratio = e1 / e2;
    }
    er[i] = (float)ratio;
}

__global__ __launch_bounds__(256) void reduce_kernel(const float* __restrict__ er,
                                                     float* __restrict__ out) {
    __shared__ double sbuf[256];
    double acc = 0.0;
    const int total = 2 * NPTS;
    for (int i = threadIdx.x; i < total; i += 256) {
        double d = (double)er[i] - (double)er[total + i];
        acc += d * d;
    }
    sbuf[threadIdx.x] = acc;
    __syncthreads();
    for (int s2 = 128; s2 > 0; s2 >>= 1) {
        if (threadIdx.x < s2) sbuf[threadIdx.x] += sbuf[threadIdx.x + s2];
        __syncthreads();
    }
    if (threadIdx.x == 0) out[0] = (float)(sbuf[0] / (double)total);
}

extern "C" void kernel_launch(void* const* d_in, const int* in_sizes, int n_in,
                              void* d_out, int out_size, void* d_ws, size_t ws_size,
                              hipStream_t stream) {
    const float* x = (const float*)d_in[0];
    const float* y = (const float*)d_in[1];
    char* ws = (char*)d_ws;

    float4*         Ps      = (float4*)(ws);                    // 524288 B
    unsigned short* origids = (unsigned short*)(ws + 524288);   // 65536 B
    float*          aabbG   = (float*)(ws + 589824);            // 12288 B
    float*          cov     = (float*)(ws + 602112);            // 786432 B
    float*          er      = (float*)(ws + 1388544);           // 131072 B
    float*          out     = (float*)d_out;

    bin_kernel<<<4, 1024, 0, stream>>>(x, y, Ps, origids, aabbG);
    knn_cov_kernel<<<8192, 256, 0, stream>>>(Ps, origids, aabbG, cov);
    eig_kernel<<<(4 * NPTS + 255) / 256, 256, 0, stream>>>(cov, er);
    reduce_kernel<<<1, 256, 0, stream>>>(er, out);
}

// Round 7
// 113.743 us; speedup vs baseline: 5.8979x; 1.2111x over previous
//
#include <hip/hip_runtime.h>
#include <hip/hip_bf16.h>
#include <math.h>

#define NPTS   8192
#define KNN    16
#define G      16
#define NCELL  (G * G * G)
#define NCHUNK 128              // 64-point chunks per cloud

// Fixed standard-normal quantile boundaries (i/16). Only affect load balance,
// never correctness.
__constant__ float c_B[17] = {
    -1e30f,
    -1.5341205f, -1.1503494f, -0.8871466f, -0.6744898f, -0.4887764f,
    -0.3186394f, -0.1573107f,  0.0f,        0.1573107f,  0.3186394f,
     0.4887764f,  0.6744898f,  0.8871466f,  1.1503494f,  1.5341205f,
     1e30f
};

__device__ __forceinline__ int cellOf(float v) {
    int c = 0;
#pragma unroll
    for (int i = 1; i <= 15; ++i) c += (v >= c_B[i]) ? 1 : 0;
    return c;
}

// spread 4 bits to positions 0,3,6,9
__device__ __forceinline__ int spread3(int v) {
    v = (v | (v << 4)) & 0x0C3;
    v = (v | (v << 2)) & 0x249;
    return v;
}

__device__ __forceinline__ int mortonCell(float px, float py, float pz) {
    return (spread3(cellOf(px)) << 2) | (spread3(cellOf(py)) << 1) | spread3(cellOf(pz));
}

// prev-lane within each 16-lane row (DPP row_shr:1); row-head lanes masked by caller.
__device__ __forceinline__ float dpp_prev_f(float v) {
    int r = __builtin_amdgcn_update_dpp(0, __float_as_int(v), 0x111, 0xF, 0xF, false);
    return __int_as_float(r);
}
__device__ __forceinline__ int dpp_prev_i(int v) {
    return __builtin_amdgcn_update_dpp(0, v, 0x111, 0xF, 0xF, false);
}

// 16-lane sum, replicated in all 16 lanes of each row. Pure-DPP (no LDS pipe).
// Pairing tree identical to the xor1/2/4/8 ladder on group-uniform values.
__device__ __forceinline__ float sum16(float v) {
    int b;
    b = __builtin_amdgcn_update_dpp(0, __float_as_int(v), 0xB1, 0xF, 0xF, false);  // quad_perm xor1
    v += __int_as_float(b);
    b = __builtin_amdgcn_update_dpp(0, __float_as_int(v), 0x4E, 0xF, 0xF, false);  // quad_perm xor2
    v += __int_as_float(b);
    b = __builtin_amdgcn_update_dpp(0, __float_as_int(v), 0x141, 0xF, 0xF, false); // row_half_mirror
    v += __int_as_float(b);
    b = __builtin_amdgcn_update_dpp(0, __float_as_int(v), 0x140, 0xF, 0xF, false); // row_mirror
    v += __int_as_float(b);
    return v;
}

// ---------------- A1: per-part histogram (32 blocks: cloud = b>>3, part = b&7) -------
__global__ __launch_bounds__(256) void count_kernel(
    const float* __restrict__ x, const float* __restrict__ y,
    unsigned int* __restrict__ cellcnt /* [4][NCELL] */) {

    __shared__ unsigned int h[NCELL];
    const int tid   = threadIdx.x;
    const int cloud = blockIdx.x >> 3;
    const int part  = blockIdx.x & 7;
    const float* __restrict__ src = (cloud < 2 ? x : y) + (size_t)(cloud & 1) * NPTS * 3;

    for (int i = tid; i < NCELL; i += 256) h[i] = 0;
    __syncthreads();
#pragma unroll
    for (int k = 0; k < 4; ++k) {
        int p = (part << 10) | (k << 8) | tid;
        atomicAdd(&h[mortonCell(src[3 * p], src[3 * p + 1], src[3 * p + 2])], 1u);
    }
    __syncthreads();
    for (int i = tid; i < NCELL; i += 256)
        if (h[i]) atomicAdd(&cellcnt[cloud * NCELL + i], h[i]);
}

// ---------------- A2: exclusive scan per cloud (4 blocks x 1024), in place ----------
__global__ __launch_bounds__(1024) void scan_kernel(unsigned int* __restrict__ cellcnt) {
    __shared__ unsigned int scanbuf[1024];
    const int tid = threadIdx.x;
    unsigned int* cc = cellcnt + blockIdx.x * NCELL;

    unsigned int c0 = cc[4 * tid], c1 = cc[4 * tid + 1];
    unsigned int c2 = cc[4 * tid + 2], c3 = cc[4 * tid + 3];
    unsigned int ssum = c0 + c1 + c2 + c3;
    scanbuf[tid] = ssum;
    __syncthreads();
    for (int d = 1; d < 1024; d <<= 1) {
        unsigned int v = scanbuf[tid];
        unsigned int w = (tid >= d) ? scanbuf[tid - d] : 0;
        __syncthreads();
        scanbuf[tid] = v + w;
        __syncthreads();
    }
    unsigned int excl = scanbuf[tid] - ssum;
    cc[4 * tid]     = excl;
    cc[4 * tid + 1] = excl + c0;
    cc[4 * tid + 2] = excl + c0 + c1;
    cc[4 * tid + 3] = excl + c0 + c1 + c2;
}

// ---------------- A3: scatter via atomic ticket (32 blocks) -------------------------
__global__ __launch_bounds__(256) void scatter_kernel(
    const float* __restrict__ x, const float* __restrict__ y,
    unsigned int* __restrict__ cellcnt,
    float4* __restrict__ Ps, unsigned short* __restrict__ origids) {

    const int tid   = threadIdx.x;
    const int cloud = blockIdx.x >> 3;
    const int part  = blockIdx.x & 7;
    const float* __restrict__ src = (cloud < 2 ? x : y) + (size_t)(cloud & 1) * NPTS * 3;

#pragma unroll
    for (int k = 0; k < 4; ++k) {
        int p = (part << 10) | (k << 8) | tid;
        float px = src[3 * p], py = src[3 * p + 1], pz = src[3 * p + 2];
        int c = mortonCell(px, py, pz);
        unsigned int pos = atomicAdd(&cellcnt[cloud * NCELL + c], 1u);
        Ps[(cloud << 13) + pos] = make_float4(-2.f * px, -2.f * py, -2.f * pz,
                                              px * px + py * py + pz * pz);
        origids[(cloud << 13) + pos] = (unsigned short)p;
    }
}

// ---------------- A4: chunk AABBs, one wave per chunk (512 waves) -------------------
__global__ __launch_bounds__(256) void aabb_kernel(
    const float4* __restrict__ Ps, float* __restrict__ aabbG /* [4][6][NCHUNK] */) {

    const int tid  = threadIdx.x;
    const int lane = tid & 63;
    const int w    = (blockIdx.x << 2) | (tid >> 6);   // 0..511
    const int cloud = w >> 7;
    const int c     = w & 127;

    float4 f = Ps[(cloud << 13) | (c << 6) | lane];
    float px = -0.5f * f.x, py = -0.5f * f.y, pz = -0.5f * f.z;
    float lx = px, hx = px, ly = py, hy = py, lz = pz, hz = pz;
#pragma unroll
    for (int s = 1; s < 64; s <<= 1) {
        lx = fminf(lx, __shfl_xor(lx, s)); hx = fmaxf(hx, __shfl_xor(hx, s));
        ly = fminf(ly, __shfl_xor(ly, s)); hy = fmaxf(hy, __shfl_xor(hy, s));
        lz = fminf(lz, __shfl_xor(lz, s)); hz = fmaxf(hz, __shfl_xor(hz, s));
    }
    if (lane == 0) {
        float* ab = aabbG + cloud * (6 * NCHUNK);
        ab[0 * NCHUNK + c] = lx; ab[1 * NCHUNK + c] = hx;
        ab[2 * NCHUNK + c] = ly; ab[3 * NCHUNK + c] = hy;
        ab[4 * NCHUNK + c] = lz; ab[5 * NCHUNK + c] = hz;
    }
}

// ---------------- Kernel B: best-first chunk-pruned kNN + covariance, 1 wave/query ---
__global__ __launch_bounds__(256) void knn_cov_kernel(
    const float4* __restrict__ Ps, const unsigned short* __restrict__ origids,
    const float* __restrict__ aabbG, float* __restrict__ cov) {

    __shared__ float sA[6 * NCHUNK];   // SoA AABB table for this block's cloud (3 KiB)

    const int tid  = threadIdx.x;
    const int lane = tid & 63;
    const int wv   = tid >> 6;
    const int cloud = blockIdx.x >> 11;
    const int s     = ((blockIdx.x << 2) | wv) & (NPTS - 1);   // sorted position

    for (int i = tid; i < 6 * NCHUNK; i += 256) sA[i] = aabbG[cloud * (6 * NCHUNK) + i];
    __syncthreads();

    const float4* __restrict__ Pc = Ps + (cloud << 13);
    const float4 qp = Pc[s];
    const float sqq = qp.w;
    const float qx = -0.5f * qp.x, qy = -0.5f * qp.y, qz = -0.5f * qp.z;
    const int co = s >> 6;   // own chunk

    float valV, thr;
    int   idxV;

    // --- Seed: 64-lane bitonic sort of own chunk (includes self) ---
    {
        int pos = (co << 6) | lane;
        float4 f = Pc[pos];
        float k = fmaf(qx, f.x, fmaf(qy, f.y, fmaf(qz, f.z, sqq + f.w)));
        int p = pos;
#pragma unroll
        for (int size = 2; size <= 64; size <<= 1) {
#pragma unroll
            for (int stride = size >> 1; stride >= 1; stride >>= 1) {
                float ok = __shfl_xor(k, stride);
                int   op = __shfl_xor(p, stride);
                bool up = ((lane & size) == 0);
                bool lower = ((lane & stride) == 0);
                bool want_min = (up == lower);
                bool take = want_min ? (ok < k) : (ok > k);
                k = take ? ok : k;
                p = take ? op : p;
            }
        }
        valV = __shfl(k, lane & 15);
        idxV = __shfl(p, lane & 15);
        thr  = __shfl(k, 15);
    }

    // --- Chunk AABB bounds: 2 chunks per lane (groups of 64 chunk ids) ---
    float bval[2];
#pragma unroll
    for (int g = 0; g < 2; ++g) {
        int c = (g << 6) | lane;
        float dxl = fmaxf(0.f, fmaxf(sA[c] - qx, qx - sA[NCHUNK + c]));
        float dyl = fmaxf(0.f, fmaxf(sA[2 * NCHUNK + c] - qy, qy - sA[3 * NCHUNK + c]));
        float dzl = fmaxf(0.f, fmaxf(sA[4 * NCHUNK + c] - qz, qz - sA[5 * NCHUNK + c]));
        bval[g] = dxl * dxl + dyl * dyl + dzl * dzl;
    }
    unsigned long long rem0 = ~0ull, rem1 = ~0ull;
    if (co < 64) rem0 &= ~(1ull << co); else rem1 &= ~(1ull << (co - 64));

    // --- Best-first scan: process unvisited chunks in ~nearest-bound order.
    // 32-bit key: bound-bits (low 7 mantissa bits dropped) | chunk id. Ordering is
    // heuristic only; correctness comes from (bound < thr) + rem mask.
    for (;;) {
        unsigned long long live0 = rem0 & __ballot(bval[0] < thr);
        unsigned long long live1 = rem1 & __ballot(bval[1] < thr);
        if (!(live0 | live1)) break;

        unsigned int k0 = ((live0 >> lane) & 1)
            ? ((__float_as_uint(bval[0]) & 0xFFFFFF80u) | (unsigned)lane) : 0xFFFFFFFFu;
        unsigned int k1 = ((live1 >> lane) & 1)
            ? ((__float_as_uint(bval[1]) & 0xFFFFFF80u) | (unsigned)(64 + lane)) : 0xFFFFFFFFu;
        unsigned int kk = k0 < k1 ? k0 : k1;
#pragma unroll
        for (int w = 1; w < 64; w <<= 1) {
            unsigned int ok = __shfl_xor(kk, w);
            kk = ok < kk ? ok : kk;
        }
        int cid = (int)(kk & 127u);
        if (cid < 64) rem0 &= ~(1ull << cid); else rem1 &= ~(1ull << (cid - 64));

        // scan chunk cid
        int pos = (cid << 6) | lane;
        float4 f = Pc[pos];
        float d2 = fmaf(qx, f.x, fmaf(qy, f.y, fmaf(qz, f.z, sqq + f.w)));
        unsigned long long m = __ballot(d2 < thr);
        if (m) {
            do {
                int li = __builtin_ctzll(m); m &= m - 1;
                float sv = __int_as_float(
                    __builtin_amdgcn_readlane(__float_as_int(d2), li));
                int sj = __builtin_amdgcn_readlane(pos, li);
                float pv = dpp_prev_f(valV);
                int   pi = dpp_prev_i(idxV);
                bool keep  = (valV <= sv);
                bool fromv = ((lane & 15) == 0) || (pv <= sv);
                float nv = keep ? valV : (fromv ? sv : pv);
                int   ni = keep ? idxV : (fromv ? sj : pi);
                valV = nv; idxV = ni;
            } while (m);
            thr = __int_as_float(__builtin_amdgcn_readlane(__float_as_int(valV), 15));
        }
    }

    // --- Covariance of the 16 selected (lanes of each 16-row hold one neighbor each) ---
    float4 nf = Pc[idxV];
    float nx = -0.5f * nf.x, ny = -0.5f * nf.y, nz = -0.5f * nf.z;

    const float invk = 1.0f / KNN;
    float mx = sum16(nx) * invk;
    float my = sum16(ny) * invk;
    float mz = sum16(nz) * invk;

    float dx = nx - mx, dy = ny - my, dz = nz - mz;
    float c00 = sum16(dx * dx), c01 = sum16(dx * dy), c02 = sum16(dx * dz);
    float c11 = sum16(dy * dy), c12 = sum16(dy * dz), c22 = sum16(dz * dz);

    if (lane == 0) {
        int orig = origids[(cloud << 13) + s];
        float* cp = cov + ((size_t)(cloud << 13) + orig) * 6;
        cp[0] = c00 * invk; cp[1] = c01 * invk; cp[2] = c02 * invk;
        cp[3] = c11 * invk; cp[4] = c12 * invk; cp[5] = c22 * invk;
    }
}

// ---------------- eig + reduce ------------------------------------------------------
__global__ __launch_bounds__(256) void eig_kernel(const float* __restrict__ cov,
                                                  float* __restrict__ er) {
    int i = blockIdx.x * 256 + threadIdx.x;
    if (i >= 4 * NPTS) return;
    const float* cp = cov + (size_t)i * 6;
    double a00 = cp[0], a01 = cp[1], a02 = cp[2];
    double a11 = cp[3], a12 = cp[4], a22 = cp[5];

    double qm = (a00 + a11 + a22) * (1.0 / 3.0);
    double p1 = a01 * a01 + a02 * a02 + a12 * a12;
    double b00 = a00 - qm, b11 = a11 - qm, b22 = a22 - qm;
    double p2 = b00 * b00 + b11 * b11 + b22 * b22 + 2.0 * p1;

    double ratio;
    if (p2 <= 0.0) {
        ratio = 1.0;
    } else {
        double p = sqrt(p2 * (1.0 / 6.0));
        double inv = 1.0 / p;
        double m00 = b00 * inv, m11 = b11 * inv, m22 = b22 * inv;
        double m01 = a01 * inv, m02 = a02 * inv, m12 = a12 * inv;
        double detB = m00 * (m11 * m22 - m12 * m12)
                    - m01 * (m01 * m22 - m12 * m02)
                    + m02 * (m01 * m12 - m11 * m02);
        double r = 0.5 * detB;
        r = fmin(1.0, fmax(-1.0, r));
        double phi = acos(r) * (1.0 / 3.0);
        double e1 = qm + 2.0 * p * cos(phi);
        double e3 = qm + 2.0 * p * cos(phi + 2.0943951023931953);
        double e2 = 3.0 * qm - e1 - e3;
        ratio = e1 / e2;
    }
    er[i] = (float)ratio;
}

__global__ __launch_bounds__(256) void reduce_kernel(const float* __restrict__ er,
                                                     float* __restrict__ out) {
    __shared__ double sbuf[256];
    double acc = 0.0;
    const int total = 2 * NPTS;
    for (int i = threadIdx.x; i < total; i += 256) {
        double d = (double)er[i] - (double)er[total + i];
        acc += d * d;
    }
    sbuf[threadIdx.x] = acc;
    __syncthreads();
    for (int s2 = 128; s2 > 0; s2 >>= 1) {
        if (threadIdx.x < s2) sbuf[threadIdx.x] += sbuf[threadIdx.x + s2];
        __syncthreads();
    }
    if (threadIdx.x == 0) out[0] = (float)(sbuf[0] / (double)total);
}

extern "C" void kernel_launch(void* const* d_in, const int* in_sizes, int n_in,
                              void* d_out, int out_size, void* d_ws, size_t ws_size,
                              hipStream_t stream) {
    const float* x = (const float*)d_in[0];
    const float* y = (const float*)d_in[1];
    char* ws = (char*)d_ws;

    float4*         Ps      = (float4*)(ws);                    // 524288 B
    unsigned short* origids = (unsigned short*)(ws + 524288);   // 65536 B
    float*          aabbG   = (float*)(ws + 589824);            // 12288 B
    float*          cov     = (float*)(ws + 602112);            // 786432 B
    float*          er      = (float*)(ws + 1388544);           // 131072 B
    unsigned int*   cellcnt = (unsigned int*)(ws + 1519616);    // 65536 B
    float*          out     = (float*)d_out;

    hipMemsetAsync(cellcnt, 0, 4 * NCELL * sizeof(unsigned int), stream);
    count_kernel<<<32, 256, 0, stream>>>(x, y, cellcnt);
    scan_kernel<<<4, 1024, 0, stream>>>(cellcnt);
    scatter_kernel<<<32, 256, 0, stream>>>(x, y, cellcnt, Ps, origids);
    aabb_kernel<<<128, 256, 0, stream>>>(Ps, aabbG);
    knn_cov_kernel<<<8192, 256, 0, stream>>>(Ps, origids, aabbG, cov);
    eig_kernel<<<(4 * NPTS + 255) / 256, 256, 0, stream>>>(cov, er);
    reduce_kernel<<<1, 256, 0, stream>>>(er, out);
}

// Round 8
// 95.678 us; speedup vs baseline: 7.0115x; 1.1888x over previous
//
#include <hip/hip_runtime.h>
#include <hip/hip_bf16.h>
#include <math.h>

#define NPTS   8192
#define KNN    16
#define G      16
#define NCELL  (G * G * G)
#define NCHUNK 128              // 64-point chunks per cloud
#define NPART  4                // scatter/count partitions per cloud

// Fixed standard-normal quantile boundaries (i/16). Only affect load balance,
// never correctness.
__constant__ float c_B[17] = {
    -1e30f,
    -1.5341205f, -1.1503494f, -0.8871466f, -0.6744898f, -0.4887764f,
    -0.3186394f, -0.1573107f,  0.0f,        0.1573107f,  0.3186394f,
     0.4887764f,  0.6744898f,  0.8871466f,  1.1503494f,  1.5341205f,
     1e30f
};

__device__ __forceinline__ int cellOf(float v) {
    int c = 0;
#pragma unroll
    for (int i = 1; i <= 15; ++i) c += (v >= c_B[i]) ? 1 : 0;
    return c;
}

// spread 4 bits to positions 0,3,6,9
__device__ __forceinline__ int spread3(int v) {
    v = (v | (v << 4)) & 0x0C3;
    v = (v | (v << 2)) & 0x249;
    return v;
}

__device__ __forceinline__ int mortonCell(float px, float py, float pz) {
    return (spread3(cellOf(px)) << 2) | (spread3(cellOf(py)) << 1) | spread3(cellOf(pz));
}

// prev-lane within each 16-lane row (DPP row_shr:1); row-head lanes masked by caller.
__device__ __forceinline__ float dpp_prev_f(float v) {
    int r = __builtin_amdgcn_update_dpp(0, __float_as_int(v), 0x111, 0xF, 0xF, false);
    return __int_as_float(r);
}
__device__ __forceinline__ int dpp_prev_i(int v) {
    return __builtin_amdgcn_update_dpp(0, v, 0x111, 0xF, 0xF, false);
}

// 16-lane sum, replicated in all 16 lanes of each row. Pure-DPP (no LDS pipe).
__device__ __forceinline__ float sum16(float v) {
    int b;
    b = __builtin_amdgcn_update_dpp(0, __float_as_int(v), 0xB1, 0xF, 0xF, false);  // quad_perm xor1
    v += __int_as_float(b);
    b = __builtin_amdgcn_update_dpp(0, __float_as_int(v), 0x4E, 0xF, 0xF, false);  // quad_perm xor2
    v += __int_as_float(b);
    b = __builtin_amdgcn_update_dpp(0, __float_as_int(v), 0x141, 0xF, 0xF, false); // row_half_mirror
    v += __int_as_float(b);
    b = __builtin_amdgcn_update_dpp(0, __float_as_int(v), 0x140, 0xF, 0xF, false); // row_mirror
    v += __int_as_float(b);
    return v;
}

// ---------------- A1: per-(cloud,part) histogram, no global atomics -----------------
// cellcnt layout: [cloud][part][cell]
__global__ __launch_bounds__(256) void count_kernel(
    const float* __restrict__ x, const float* __restrict__ y,
    unsigned int* __restrict__ cellcnt) {

    __shared__ unsigned int h[NCELL];
    const int tid   = threadIdx.x;
    const int cloud = blockIdx.x >> 2;
    const int part  = blockIdx.x & 3;
    const float* __restrict__ src = (cloud < 2 ? x : y) + (size_t)(cloud & 1) * NPTS * 3;

    for (int i = tid; i < NCELL; i += 256) h[i] = 0;
    __syncthreads();
#pragma unroll
    for (int k = 0; k < 8; ++k) {
        int p = (part << 11) | (k << 8) | tid;
        atomicAdd(&h[mortonCell(src[3 * p], src[3 * p + 1], src[3 * p + 2])], 1u);
    }
    __syncthreads();
    unsigned int* cc = cellcnt + (cloud * NPART + part) * NCELL;
    for (int i = tid; i < NCELL; i += 256) cc[i] = h[i];
}

// ---------------- A2: per-cloud scan over (cell, part) in place ---------------------
__global__ __launch_bounds__(1024) void scan_kernel(unsigned int* __restrict__ cellcnt) {
    __shared__ unsigned int scanbuf[1024];
    const int tid = threadIdx.x;
    unsigned int* cc = cellcnt + blockIdx.x * (NPART * NCELL);   // [part][cell]

    unsigned int v[NPART][4], csum[4];
    unsigned int ssum = 0;
#pragma unroll
    for (int j = 0; j < 4; ++j) {
        int cell = 4 * tid + j;
        unsigned int s = 0;
#pragma unroll
        for (int p = 0; p < NPART; ++p) { v[p][j] = cc[p * NCELL + cell]; s += v[p][j]; }
        csum[j] = s; ssum += s;
    }
    scanbuf[tid] = ssum;
    __syncthreads();
    for (int d = 1; d < 1024; d <<= 1) {
        unsigned int a = scanbuf[tid];
        unsigned int w = (tid >= d) ? scanbuf[tid - d] : 0;
        __syncthreads();
        scanbuf[tid] = a + w;
        __syncthreads();
    }
    unsigned int run = scanbuf[tid] - ssum;
#pragma unroll
    for (int j = 0; j < 4; ++j) {
        int cell = 4 * tid + j;
        unsigned int pr = run;
#pragma unroll
        for (int p = 0; p < NPART; ++p) { cc[p * NCELL + cell] = pr; pr += v[p][j]; }
        run += csum[j];
    }
}

// ---------------- A3: scatter via atomic ticket on [cloud][part][cell] --------------
__global__ __launch_bounds__(256) void scatter_kernel(
    const float* __restrict__ x, const float* __restrict__ y,
    unsigned int* __restrict__ cellcnt,
    float4* __restrict__ Ps, unsigned short* __restrict__ origids) {

    const int tid   = threadIdx.x;
    const int cloud = blockIdx.x >> 2;
    const int part  = blockIdx.x & 3;
    const float* __restrict__ src = (cloud < 2 ? x : y) + (size_t)(cloud & 1) * NPTS * 3;
    unsigned int* cc = cellcnt + (cloud * NPART + part) * NCELL;

#pragma unroll
    for (int k = 0; k < 8; ++k) {
        int p = (part << 11) | (k << 8) | tid;
        float px = src[3 * p], py = src[3 * p + 1], pz = src[3 * p + 2];
        int c = mortonCell(px, py, pz);
        unsigned int pos = atomicAdd(&cc[c], 1u);
        Ps[(cloud << 13) + pos] = make_float4(-2.f * px, -2.f * py, -2.f * pz,
                                              px * px + py * py + pz * pz);
        origids[(cloud << 13) + pos] = (unsigned short)p;
    }
}

// ---------------- A4: chunk AABBs, one wave per chunk -------------------------------
__global__ __launch_bounds__(256) void aabb_kernel(
    const float4* __restrict__ Ps, float* __restrict__ aabbG /* [4][6][NCHUNK] */) {

    const int tid  = threadIdx.x;
    const int lane = tid & 63;
    const int w    = (blockIdx.x << 2) | (tid >> 6);   // 0..511
    const int cloud = w >> 7;
    const int c     = w & 127;

    float4 f = Ps[(cloud << 13) | (c << 6) | lane];
    float px = -0.5f * f.x, py = -0.5f * f.y, pz = -0.5f * f.z;
    float lx = px, hx = px, ly = py, hy = py, lz = pz, hz = pz;
#pragma unroll
    for (int s = 1; s < 64; s <<= 1) {
        lx = fminf(lx, __shfl_xor(lx, s)); hx = fmaxf(hx, __shfl_xor(hx, s));
        ly = fminf(ly, __shfl_xor(ly, s)); hy = fmaxf(hy, __shfl_xor(hy, s));
        lz = fminf(lz, __shfl_xor(lz, s)); hz = fmaxf(hz, __shfl_xor(hz, s));
    }
    if (lane == 0) {
        float* ab = aabbG + cloud * (6 * NCHUNK);
        ab[0 * NCHUNK + c] = lx; ab[1 * NCHUNK + c] = hx;
        ab[2 * NCHUNK + c] = ly; ab[3 * NCHUNK + c] = hy;
        ab[4 * NCHUNK + c] = lz; ab[5 * NCHUNK + c] = hz;
    }
}

// ---------------- Kernel B: best-first (dual-pop, preloaded) kNN + covariance -------
__global__ __launch_bounds__(256) void knn_cov_kernel(
    const float4* __restrict__ Ps, const unsigned short* __restrict__ origids,
    const float* __restrict__ aabbG, float* __restrict__ cov) {

    __shared__ float sA[6 * NCHUNK];   // SoA AABB table (3 KiB)

    const int tid  = threadIdx.x;
    const int lane = tid & 63;
    const int wv   = tid >> 6;
    const int cloud = blockIdx.x >> 11;
    const int s     = ((blockIdx.x << 2) | wv) & (NPTS - 1);   // sorted position

    for (int i = tid; i < 6 * NCHUNK; i += 256) sA[i] = aabbG[cloud * (6 * NCHUNK) + i];
    __syncthreads();

    const float4* __restrict__ Pc = Ps + (cloud << 13);
    const float4 qp = Pc[s];
    const float sqq = qp.w;
    const float qx = -0.5f * qp.x, qy = -0.5f * qp.y, qz = -0.5f * qp.z;
    const int co = s >> 6;   // own chunk

    // --- Chunk AABB bounds: 2 chunks per lane ---
    float bval[2];
#pragma unroll
    for (int g = 0; g < 2; ++g) {
        int c = (g << 6) | lane;
        float dxl = fmaxf(0.f, fmaxf(sA[c] - qx, qx - sA[NCHUNK + c]));
        float dyl = fmaxf(0.f, fmaxf(sA[2 * NCHUNK + c] - qy, qy - sA[3 * NCHUNK + c]));
        float dzl = fmaxf(0.f, fmaxf(sA[4 * NCHUNK + c] - qz, qz - sA[5 * NCHUNK + c]));
        bval[g] = dxl * dxl + dyl * dyl + dzl * dzl;
    }
    unsigned long long rem0 = ~0ull, rem1 = ~0ull;
    if (co < 64) rem0 &= ~(1ull << co); else rem1 &= ~(1ull << (co - 64));

    // dual (min, 2nd-min) reduce over keyed bounds restricted to given live masks.
    // key = bound-bits (low 7 mantissa dropped) | chunk id; ordering heuristic only.
    auto dual_argmin = [&](unsigned long long live0, unsigned long long live1,
                           int& cidA, int& cidB, bool& hasA, bool& hasB) {
        unsigned int k0 = ((live0 >> lane) & 1)
            ? ((__float_as_uint(bval[0]) & 0xFFFFFF80u) | (unsigned)lane) : 0xFFFFFFFFu;
        unsigned int k1 = ((live1 >> lane) & 1)
            ? ((__float_as_uint(bval[1]) & 0xFFFFFF80u) | (unsigned)(64 + lane)) : 0xFFFFFFFFu;
        unsigned int a = min(k0, k1), b = max(k0, k1);
#pragma unroll
        for (int w = 1; w < 64; w <<= 1) {
            unsigned int oa = __shfl_xor(a, w);
            unsigned int ob = __shfl_xor(b, w);
            unsigned int mn = min(a, oa), mx = max(a, oa);
            unsigned int c2 = (a < oa) ? b : ob;
            a = mn; b = min(mx, c2);
        }
        hasA = (a != 0xFFFFFFFFu); cidA = (int)(a & 127u);
        hasB = (b != 0xFFFFFFFFu); cidB = (int)(b & 127u);
    };
    auto clear_rem = [&](int cid) {
        if (cid < 64) rem0 &= ~(1ull << cid); else rem1 &= ~(1ull << (cid - 64));
    };
    auto bound_of = [&](int cid) {
        return __int_as_float(__builtin_amdgcn_readlane(
            __float_as_int(bval[cid >> 6]), cid & 63));
    };

    // --- Preload the two nearest non-own chunks (loads in flight during seed) ---
    int pA, pB; bool hA, hB;
    dual_argmin(rem0, rem1, pA, pB, hA, hB);
    clear_rem(pA); clear_rem(pB);
    float4 pfA = Pc[(pA << 6) | lane];
    float4 pfB = Pc[(pB << 6) | lane];

    // --- Seed: 64-lane bitonic sort of own chunk (includes self) ---
    float valV, thr;
    int   idxV;
    {
        int pos = (co << 6) | lane;
        float4 f = Pc[pos];
        float k = fmaf(qx, f.x, fmaf(qy, f.y, fmaf(qz, f.z, sqq + f.w)));
        int p = pos;
#pragma unroll
        for (int size = 2; size <= 64; size <<= 1) {
#pragma unroll
            for (int stride = size >> 1; stride >= 1; stride >>= 1) {
                float ok = __shfl_xor(k, stride);
                int   op = __shfl_xor(p, stride);
                bool up = ((lane & size) == 0);
                bool lower = ((lane & stride) == 0);
                bool want_min = (up == lower);
                bool take = want_min ? (ok < k) : (ok > k);
                k = take ? ok : k;
                p = take ? op : p;
            }
        }
        valV = __shfl(k, lane & 15);
        idxV = __shfl(p, lane & 15);
        thr  = __shfl(k, 15);
    }

    // Process one loaded chunk: ballot + waterfall insert + thr update.
    auto process = [&](float4 f, int cid) {
        float d2 = fmaf(qx, f.x, fmaf(qy, f.y, fmaf(qz, f.z, sqq + f.w)));
        unsigned long long m = __ballot(d2 < thr);
        if (m) {
            do {
                int li = __builtin_ctzll(m); m &= m - 1;
                float sv = __int_as_float(
                    __builtin_amdgcn_readlane(__float_as_int(d2), li));
                int sj = (cid << 6) | li;
                float pv = dpp_prev_f(valV);
                int   pi = dpp_prev_i(idxV);
                bool keep  = (valV <= sv);
                bool fromv = ((lane & 15) == 0) || (pv <= sv);
                float nv = keep ? valV : (fromv ? sv : pv);
                int   ni = keep ? idxV : (fromv ? sj : pi);
                valV = nv; idxV = ni;
            } while (m);
            thr = __int_as_float(__builtin_amdgcn_readlane(__float_as_int(valV), 15));
        }
    };

    // consume preloads (clearing even when bound >= thr is safe: bound >= thr_now
    // >= thr_final, so no member can enter the final top-16)
    if (bound_of(pA) < thr) process(pfA, pA);
    if (bound_of(pB) < thr) process(pfB, pB);

    // --- Best-first rounds, popping two chunks per round ---
    for (;;) {
        unsigned long long live0 = rem0 & __ballot(bval[0] < thr);
        unsigned long long live1 = rem1 & __ballot(bval[1] < thr);
        if (!(live0 | live1)) break;

        int cidA, cidB; bool hasA, hasB;
        dual_argmin(live0, live1, cidA, cidB, hasA, hasB);
        clear_rem(cidA);
        if (hasB) clear_rem(cidB);

        float4 fA = Pc[(cidA << 6) | lane];
        float4 fB;
        if (hasB) fB = Pc[(cidB << 6) | lane];

        process(fA, cidA);
        if (hasB && bound_of(cidB) < thr) process(fB, cidB);
    }

    // --- Covariance of the 16 selected ---
    float4 nf = Pc[idxV];
    float nx = -0.5f * nf.x, ny = -0.5f * nf.y, nz = -0.5f * nf.z;

    const float invk = 1.0f / KNN;
    float mx = sum16(nx) * invk;
    float my = sum16(ny) * invk;
    float mz = sum16(nz) * invk;

    float dx = nx - mx, dy = ny - my, dz = nz - mz;
    float c00 = sum16(dx * dx), c01 = sum16(dx * dy), c02 = sum16(dx * dz);
    float c11 = sum16(dy * dy), c12 = sum16(dy * dz), c22 = sum16(dz * dz);

    if (lane == 0) {
        int orig = origids[(cloud << 13) + s];
        float* cp = cov + ((size_t)(cloud << 13) + orig) * 6;
        cp[0] = c00 * invk; cp[1] = c01 * invk; cp[2] = c02 * invk;
        cp[3] = c11 * invk; cp[4] = c12 * invk; cp[5] = c22 * invk;
    }
}

// ---------------- eig + reduce (fused) ----------------------------------------------
__device__ double eig_ratio(const float* __restrict__ cp) {
    double a00 = cp[0], a01 = cp[1], a02 = cp[2];
    double a11 = cp[3], a12 = cp[4], a22 = cp[5];

    double qm = (a00 + a11 + a22) * (1.0 / 3.0);
    double p1 = a01 * a01 + a02 * a02 + a12 * a12;
    double b00 = a00 - qm, b11 = a11 - qm, b22 = a22 - qm;
    double p2 = b00 * b00 + b11 * b11 + b22 * b22 + 2.0 * p1;

    if (p2 <= 0.0) return 1.0;
    double p = sqrt(p2 * (1.0 / 6.0));
    double inv = 1.0 / p;
    double m00 = b00 * inv, m11 = b11 * inv, m22 = b22 * inv;
    double m01 = a01 * inv, m02 = a02 * inv, m12 = a12 * inv;
    double detB = m00 * (m11 * m22 - m12 * m12)
                - m01 * (m01 * m22 - m12 * m02)
                + m02 * (m01 * m12 - m11 * m02);
    double r = 0.5 * detB;
    r = fmin(1.0, fmax(-1.0, r));
    double phi = acos(r) * (1.0 / 3.0);
    double e1 = qm + 2.0 * p * cos(phi);
    double e3 = qm + 2.0 * p * cos(phi + 2.0943951023931953);
    double e2 = 3.0 * qm - e1 - e3;
    return e1 / e2;
}

__global__ __launch_bounds__(256) void eigred_kernel(const float* __restrict__ cov,
                                                     double* __restrict__ partial) {
    __shared__ double sb[256];
    const int i = blockIdx.x * 256 + threadIdx.x;   // 0..16383 (batch-major pairs)
    double r1 = eig_ratio(cov + (size_t)i * 6);
    double r2 = eig_ratio(cov + (size_t)(2 * NPTS + i) * 6);
    double d = r1 - r2;
    sb[threadIdx.x] = d * d;
    __syncthreads();
    for (int s2 = 128; s2 > 0; s2 >>= 1) {
        if (threadIdx.x < s2) sb[threadIdx.x] += sb[threadIdx.x + s2];
        __syncthreads();
    }
    if (threadIdx.x == 0) partial[blockIdx.x] = sb[0];
}

__global__ __launch_bounds__(64) void final_kernel(const double* __restrict__ partial,
                                                   float* __restrict__ out) {
    double v = partial[threadIdx.x];
#pragma unroll
    for (int w = 1; w < 64; w <<= 1) v += __shfl_xor(v, w);
    if (threadIdx.x == 0) out[0] = (float)(v / (double)(2 * NPTS));
}

extern "C" void kernel_launch(void* const* d_in, const int* in_sizes, int n_in,
                              void* d_out, int out_size, void* d_ws, size_t ws_size,
                              hipStream_t stream) {
    const float* x = (const float*)d_in[0];
    const float* y = (const float*)d_in[1];
    char* ws = (char*)d_ws;

    float4*         Ps      = (float4*)(ws);                    // 524288 B
    unsigned short* origids = (unsigned short*)(ws + 524288);   // 65536 B
    float*          aabbG   = (float*)(ws + 589824);            // 12288 B
    float*          cov     = (float*)(ws + 602112);            // 786432 B
    unsigned int*   cellcnt = (unsigned int*)(ws + 1388544);    // 262144 B
    double*         partial = (double*)(ws + 1650688);          // 512 B
    float*          out     = (float*)d_out;

    count_kernel<<<4 * NPART, 256, 0, stream>>>(x, y, cellcnt);
    scan_kernel<<<4, 1024, 0, stream>>>(cellcnt);
    scatter_kernel<<<4 * NPART, 256, 0, stream>>>(x, y, cellcnt, Ps, origids);
    aabb_kernel<<<128, 256, 0, stream>>>(Ps, aabbG);
    knn_cov_kernel<<<8192, 256, 0, stream>>>(Ps, origids, aabbG, cov);
    eigred_kernel<<<64, 256, 0, stream>>>(cov, partial);
    final_kernel<<<1, 64, 0, stream>>>(partial, out);
}